// Round 9
// baseline (64.205 us; speedup 1.0000x reference)
//
#include <hip/hip_runtime.h>

#define GAMMA_F 1.1f
#define F_DIM 5
#define BOXG 8
#define MAX_NSEG 256
#define MAXL 1024  // max points per segment staged in LDS (8 KB)

// DIAGNOSTIC ROUND: inner work repeated REPS_SEG / REPS_GATHER times with
// idempotent stores (identical values to identical addresses every rep) so
// rocprof shows the kernels above the harness fill dispatches. asm clobbers
// block cross-rep CSE. Output is bitwise identical to REPS=1.
#define REPS_SEG 4
#define REPS_GATHER 16

__device__ __forceinline__ int prefix_lt(unsigned long long m) {
  return __builtin_amdgcn_mbcnt_hi(
      (unsigned)(m >> 32), __builtin_amdgcn_mbcnt_lo((unsigned)m, 0u));
}

template <int NWAVE>
__global__ void __launch_bounds__(NWAVE * 64, 8) seg_lds_kernel(
    const float* __restrict__ pts, const float* __restrict__ boxes,
    int* __restrict__ cnt, unsigned short* __restrict__ idx, int N, int S,
    int NSEG, int L, int NGRP) {
  __shared__ __align__(16) float2 sxy[MAXL];

  const int tid = threadIdx.x;
  const int lane = tid & 63;
  const int wid = tid >> 6;
  const int bpg = NGRP / NWAVE;  // blocks per segment
  const int seg = blockIdx.x / bpg;
  const int bg = blockIdx.x - seg * bpg;
  const int grp = bg * NWAVE + wid;
  const int box0 = grp * BOXG;

  const int start = seg * L;
  const int end = min(start + L, N);
  const int npts = end - start;

  // Per-wave box params; smax = largest f32 s with sqrt_rn(s) <= r (exact,
  // proven R2).
  float cx[BOXG], cy[BOXG], smax[BOXG];
#pragma unroll
  for (int b = 0; b < BOXG; ++b) {
    const float* bx = boxes + (box0 + b) * 7;
    cx[b] = bx[0];
    cy[b] = bx[1];
    const float hdx = __fmul_rn(bx[3], 0.5f);
    const float hdy = __fmul_rn(bx[4], 0.5f);
    const float r = __fmul_rn(
        __fsqrt_rn(__fadd_rn(__fmul_rn(hdx, hdx), __fmul_rn(hdy, hdy))),
        GAMMA_F);
    const unsigned ru = __float_as_uint(r);
    const float rsucc = __uint_as_float(ru + 1u);        // r > 0, finite
    const double m = ((double)r + (double)rsucc) * 0.5;  // exact
    const double m2 = m * m;                             // exact
    const bool incl = ((ru & 1u) == 0u);  // RN tie-to-even lands on r
    const float c1 = (float)m2;
    const double c1d = (double)c1;
    const bool keep = incl ? (c1d <= m2) : (c1d < m2);
    smax[b] = keep ? c1 : __uint_as_float(__float_as_uint(c1) - 1u);
  }

  // Stage this segment's xy into LDS (once per block).
  for (int t = tid; t < npts; t += NWAVE * 64) {
    const float* p = pts + (size_t)(start + t) * F_DIM;
    sxy[t] = make_float2(p[0], p[1]);
  }
  __syncthreads();

  const size_t ibase = ((size_t)box0 * NSEG + seg) * S;
  const int nfull = npts / 128;

  int c[BOXG];
  for (int rep = 0; rep < REPS_SEG; ++rep) {
    // Defeat cross-rep CSE: compiler may not assume these are rep-invariant.
    const float4* sxy4 = (const float4*)sxy;
    asm volatile("" : "+v"(sxy4));
    float cx0 = cx[0];
    asm volatile("" : "+v"(cx0));
    cx[0] = cx0;

#pragma unroll
    for (int b = 0; b < BOXG; ++b) c[b] = 0;

#define PROCESS_8(RELBASE, X0, Y0, X1, Y1, G0, G1)                          \
  {                                                                         \
    const int rel = (RELBASE) + 2 * lane;                                   \
    _Pragma("unroll") for (int b = 0; b < BOXG; ++b) {                      \
      const float dx0 = __fsub_rn((X0), cx[b]);                             \
      const float dy0 = __fsub_rn((Y0), cy[b]);                             \
      const float s0 = __fadd_rn(__fmul_rn(dx0, dx0), __fmul_rn(dy0, dy0)); \
      const float dx1 = __fsub_rn((X1), cx[b]);                             \
      const float dy1 = __fsub_rn((Y1), cy[b]);                             \
      const float s1 = __fadd_rn(__fmul_rn(dx1, dx1), __fmul_rn(dy1, dy1)); \
      const bool sel0 = (G0) && (s0 <= smax[b]);                            \
      const bool sel1 = (G1) && (s1 <= smax[b]);                            \
      const unsigned long long m0 = __ballot(sel0);                         \
      const unsigned long long m1 = __ballot(sel1);                         \
      if (m0 | m1) {                                                        \
        const int p0 = prefix_lt(m0);                                       \
        const int p1 = prefix_lt(m1);                                       \
        const int r0 = c[b] + p0 + p1;                                      \
        const int r1 = c[b] + p0 + (sel0 ? 1 : 0) + p1;                     \
        unsigned short* mp = idx + ibase + (size_t)b * NSEG * S;            \
        if (sel0 && r0 < S) mp[r0] = (unsigned short)rel;                   \
        if (sel1 && r1 < S) mp[r1] = (unsigned short)(rel + 1);             \
        c[b] += __popcll(m0) + __popcll(m1);                                \
      }                                                                     \
    }                                                                       \
  }

    for (int it = 0; it < nfull; ++it) {
      const float4 q = sxy4[it * 64 + lane];
      PROCESS_8(it * 128, q.x, q.y, q.z, q.w, true, true);
    }
    const int relb = nfull * 128;
    if (relb < npts) {
      const float4 q = sxy4[nfull * 64 + lane];
      const int rel = relb + 2 * lane;
      const bool g0 = (rel < npts);
      const bool g1 = (rel + 1 < npts);
      PROCESS_8(relb, q.x, q.y, q.z, q.w, g0, g1);
    }
#undef PROCESS_8
  }

  if (lane == 0) {
#pragma unroll
    for (int b = 0; b < BOXG; ++b) cnt[(box0 + b) * NSEG + seg] = min(c[b], S);
  }
}

// ------- Phase 2: per box, prefix over segment counts + gather features ------
__global__ void __launch_bounds__(256) gather_kernel(
    const float* __restrict__ pts, const int* __restrict__ cnt,
    const unsigned short* __restrict__ idx, float* __restrict__ out, int N,
    int S, int NSEG, int L) {
  const int b = blockIdx.x;
  const int tid = threadIdx.x;
  const int lane = tid & 63;
  const int wid = tid >> 6;

  __shared__ int pfx[MAX_NSEG + 1];
  __shared__ int wtot[4];
  __shared__ int woff[4];

  int v = (tid < NSEG) ? cnt[b * NSEG + tid] : 0;
  int sv = v;
#pragma unroll
  for (int d = 1; d < 64; d <<= 1) {
    const int t = __shfl_up(sv, d, 64);
    if (lane >= d) sv += t;
  }
  if (lane == 63) wtot[wid] = sv;
  __syncthreads();
  if (tid == 0) {
    int a = 0;
#pragma unroll
    for (int w = 0; w < 4; ++w) {
      woff[w] = a;
      a += wtot[w];
    }
  }
  __syncthreads();
  const int incl = sv + woff[wid];
  if (tid < NSEG) pfx[tid + 1] = incl;
  if (tid == 0) pfx[0] = 0;
  __syncthreads();

  const int total = pfx[NSEG];
  for (int rep = 0; rep < REPS_GATHER; ++rep) {
    int t2 = tid;
    asm volatile("" : "+v"(t2));  // defeat cross-rep CSE; value unchanged
    if (t2 < S) {
      float* o = out + ((size_t)b * S + t2) * F_DIM;
      if (t2 < total) {
        int lo = 0, hi = NSEG - 1;
        while (lo < hi) {
          const int mid = (lo + hi + 1) >> 1;
          if (pfx[mid] <= t2) lo = mid;
          else hi = mid - 1;
        }
        const int s = lo;
        const int gi =
            s * L + (int)idx[((size_t)b * NSEG + s) * S + (t2 - pfx[s])];
        const float* p = pts + (size_t)gi * F_DIM;
        o[0] = p[0];
        o[1] = p[1];
        o[2] = p[2];
        o[3] = p[3];
        o[4] = p[4];
      } else {
        o[0] = 0.0f;
        o[1] = 0.0f;
        o[2] = 0.0f;
        o[3] = 0.0f;
        o[4] = 0.0f;
      }
    }
  }
}

// ---------------- Fallback: proven R1 single-kernel version ----------------
template <int BLOCK>
__global__ void __launch_bounds__(BLOCK) voxel_sampler_fallback(
    const float* __restrict__ pts, const float* __restrict__ boxes,
    float* __restrict__ out, int N, int S) {
  constexpr int NW = BLOCK / 64;
  const int b = blockIdx.x;
  const int tid = threadIdx.x;
  const int lane = tid & 63;
  const int wid = tid >> 6;

  const float cx = boxes[b * 7 + 0];
  const float cy = boxes[b * 7 + 1];
  const float hdx = __fmul_rn(boxes[b * 7 + 3], 0.5f);
  const float hdy = __fmul_rn(boxes[b * 7 + 4], 0.5f);
  const float r = __fmul_rn(
      __fsqrt_rn(__fadd_rn(__fmul_rn(hdx, hdx), __fmul_rn(hdy, hdy))),
      GAMMA_F);

  __shared__ int s_wsum[NW];
  __shared__ int s_count;
  if (tid == 0) s_count = 0;
  __syncthreads();

  float* outb = out + (size_t)b * S * F_DIM;

  for (int base = 0; base < N; base += BLOCK) {
    const int i = base + tid;
    bool sel = false;
    float x = 0.0f, y = 0.0f;
    if (i < N) {
      x = pts[i * F_DIM + 0];
      y = pts[i * F_DIM + 1];
      const float ddx = __fsub_rn(x, cx);
      const float ddy = __fsub_rn(y, cy);
      const float dis =
          __fsqrt_rn(__fadd_rn(__fmul_rn(ddx, ddx), __fmul_rn(ddy, ddy)));
      sel = (dis <= r);
    }
    const unsigned long long m = __ballot(sel);
    if (lane == 0) s_wsum[wid] = __popcll(m);
    __syncthreads();
    const int cbase = s_count;
    int wbase = 0;
    int tot = 0;
#pragma unroll
    for (int w = 0; w < NW; ++w) {
      const int v = s_wsum[w];
      if (w < wid) wbase += v;
      tot += v;
    }
    const int pos = cbase + wbase + __popcll(m & ((1ULL << lane) - 1ULL));
    if (sel && pos < S) {
      float* o = outb + pos * F_DIM;
      o[0] = x;
      o[1] = y;
      o[2] = pts[i * F_DIM + 2];
      o[3] = pts[i * F_DIM + 3];
      o[4] = pts[i * F_DIM + 4];
    }
    __syncthreads();
    if (tid == 0) s_count = cbase + tot;
    __syncthreads();
    if (cbase + tot >= S) break;
  }

  __syncthreads();
  int cnt = s_count;
  if (cnt > S) cnt = S;
  for (int j = cnt * F_DIM + tid; j < S * F_DIM; j += BLOCK) outb[j] = 0.0f;
}

extern "C" void kernel_launch(void* const* d_in, const int* in_sizes, int n_in,
                              void* d_out, int out_size, void* d_ws,
                              size_t ws_size, hipStream_t stream) {
  const float* pts = (const float*)d_in[0];
  const float* boxes = (const float*)d_in[1];
  float* out = (float*)d_out;

  const int N = in_sizes[0] / F_DIM;     // 200000
  const int B = in_sizes[1] / 7;         // 256
  const int S = out_size / (B * F_DIM);  // 128

  const int NSEG = 256;
  int L = ((N + NSEG - 1) / NSEG + 1) & ~1;  // even
  const int NGRP = B / BOXG;                 // 32
  constexpr int NWAVE = 16;                  // 1024-thread blocks

  const size_t sz_cnt = (size_t)B * NSEG * sizeof(int);
  const size_t off_idx = (sz_cnt + 255) & ~(size_t)255;
  const size_t sz_idx = (size_t)B * NSEG * S * sizeof(unsigned short);
  const size_t need = off_idx + sz_idx;

  const bool fast = (ws_size >= need) && (L >= 2) && (L <= MAXL) &&
                    (L - 1 <= 65535) && (B % BOXG == 0) && (S <= 256) &&
                    (NSEG <= MAX_NSEG) && (NGRP % NWAVE == 0) &&
                    ((size_t)L * NSEG >= (size_t)N);

  if (fast) {
    char* ws = (char*)d_ws;
    int* cnt = (int*)ws;
    unsigned short* idx = (unsigned short*)(ws + off_idx);

    const int bpg = NGRP / NWAVE;  // 2
    seg_lds_kernel<NWAVE><<<NSEG * bpg, NWAVE * 64, 0, stream>>>(
        pts, boxes, cnt, idx, N, S, NSEG, L, NGRP);
    gather_kernel<<<B, 256, 0, stream>>>(pts, cnt, idx, out, N, S, NSEG, L);
  } else {
    voxel_sampler_fallback<1024><<<B, 1024, 0, stream>>>(pts, boxes, out, N,
                                                         S);
  }
}

// Round 10
// 27.045 us; speedup vs baseline: 2.3740x; 2.3740x over previous
//
#include <hip/hip_runtime.h>

#define GAMMA_F 1.1f
#define F_DIM 5
#define BOXG 8
#define MAX_NSEG 256
#define MAXL 1024  // max points per segment

typedef float f32x2 __attribute__((ext_vector_type(2)));

__device__ __forceinline__ f32x2 pk_add(f32x2 a, f32x2 b) {
  f32x2 d;
  asm("v_pk_add_f32 %0, %1, %2" : "=v"(d) : "v"(a), "v"(b));
  return d;
}
__device__ __forceinline__ f32x2 pk_mul(f32x2 a, f32x2 b) {
  f32x2 d;
  asm("v_pk_mul_f32 %0, %1, %2" : "=v"(d) : "v"(a), "v"(b));
  return d;
}

__device__ __forceinline__ int prefix_lt(unsigned long long m) {
  return __builtin_amdgcn_mbcnt_hi(
      (unsigned)(m >> 32), __builtin_amdgcn_mbcnt_lo((unsigned)m, 0u));
}

// ---- Phase 1: block = 1 segment x 16 waves x 8 boxes each. ----------------
// Inner test via packed fp32 (v_pk_add/v_pk_mul, IEEE RN per half; sub done
// as add of exactly-negated center -> bit-identical to reference compare).
// smax = largest f32 s with sqrt_rn(s) <= r (exact, proven R2).
template <int NWAVE>
__global__ void __launch_bounds__(NWAVE * 64, 4) seg_lds_kernel(
    const float* __restrict__ pts, const float* __restrict__ boxes,
    int* __restrict__ cnt, unsigned short* __restrict__ idx, int N, int S,
    int NSEG, int L, int NGRP) {
  __shared__ __align__(16) float rawf[MAXL * 5 + 4];
  __shared__ float sx[MAXL + 128];
  __shared__ float sy[MAXL + 128];

  const int tid = threadIdx.x;
  const int lane = tid & 63;
  const int wid = tid >> 6;
  const int bpg = NGRP / NWAVE;  // blocks per segment
  const int seg = blockIdx.x / bpg;
  const int bg = blockIdx.x - seg * bpg;
  const int grp = bg * NWAVE + wid;
  const int box0 = grp * BOXG;

  const int start = seg * L;
  const int end = min(start + L, N);
  const int npts = end - start;

  // --- Coalesced staging: aligned float4 slab -> raw LDS (all in-bounds) ---
  {
    const int dwStart = start * 5;
    const int dwEnd = dwStart + npts * 5;
    const int a0 = dwStart & ~3;  // 16B-aligned dword base
    const int totDw = dwEnd - a0;
    const int k4 = totDw >> 2;  // full float4s inside [a0, dwEnd)
    const float4* __restrict__ g4 = (const float4*)(pts + a0);
    float4* __restrict__ r4 = (float4*)rawf;
    for (int k = tid; k < k4; k += NWAVE * 64) r4[k] = g4[k];
    for (int d = a0 + (k4 << 2) + tid; d < dwEnd; d += NWAVE * 64)
      rawf[d - a0] = pts[d];
    __syncthreads();
    // Transpose raw -> sx/sy (stride-5 reads: 2 lanes/bank, free).
    const int off0 = dwStart - a0;
    for (int t = tid; t < npts; t += NWAVE * 64) {
      sx[t] = rawf[off0 + t * 5];
      sy[t] = rawf[off0 + t * 5 + 1];
    }
  }

  // Per-wave box params; negated centers as packed pairs.
  f32x2 ncx2[BOXG], ncy2[BOXG];
  float smax[BOXG];
#pragma unroll
  for (int b = 0; b < BOXG; ++b) {
    const float* bx = boxes + (box0 + b) * 7;
    const float cx = bx[0];
    const float cy = bx[1];
    ncx2[b][0] = -cx;
    ncx2[b][1] = -cx;
    ncy2[b][0] = -cy;
    ncy2[b][1] = -cy;
    const float hdx = __fmul_rn(bx[3], 0.5f);
    const float hdy = __fmul_rn(bx[4], 0.5f);
    const float r = __fmul_rn(
        __fsqrt_rn(__fadd_rn(__fmul_rn(hdx, hdx), __fmul_rn(hdy, hdy))),
        GAMMA_F);
    const unsigned ru = __float_as_uint(r);
    const float rsucc = __uint_as_float(ru + 1u);        // r > 0, finite
    const double m = ((double)r + (double)rsucc) * 0.5;  // exact
    const double m2 = m * m;                             // exact
    const bool incl = ((ru & 1u) == 0u);  // RN tie-to-even lands on r
    const float c1 = (float)m2;
    const double c1d = (double)c1;
    const bool keep = incl ? (c1d <= m2) : (c1d < m2);
    smax[b] = keep ? c1 : __uint_as_float(__float_as_uint(c1) - 1u);
  }
  __syncthreads();

  int c[BOXG];
#pragma unroll
  for (int b = 0; b < BOXG; ++b) c[b] = 0;

  const size_t ibase = ((size_t)box0 * NSEG + seg) * S;
  const int nfull = npts / 128;

#define PROCESS_8(RELBASE, XX, YY, G0, G1)                          \
  {                                                                 \
    const int rel = (RELBASE) + 2 * lane;                           \
    _Pragma("unroll") for (int b = 0; b < BOXG; ++b) {              \
      const f32x2 dxx = pk_add((XX), ncx2[b]);                      \
      const f32x2 dyy = pk_add((YY), ncy2[b]);                      \
      const f32x2 mxx = pk_mul(dxx, dxx);                           \
      const f32x2 myy = pk_mul(dyy, dyy);                           \
      const f32x2 ss = pk_add(mxx, myy);                            \
      const bool sel0 = (G0) && (ss[0] <= smax[b]);                 \
      const bool sel1 = (G1) && (ss[1] <= smax[b]);                 \
      const unsigned long long m0 = __ballot(sel0);                 \
      const unsigned long long m1 = __ballot(sel1);                 \
      if (m0 | m1) {                                                \
        const int p0 = prefix_lt(m0);                               \
        const int p1 = prefix_lt(m1);                               \
        const int r0 = c[b] + p0 + p1;                              \
        const int r1 = c[b] + p0 + (sel0 ? 1 : 0) + p1;             \
        unsigned short* mp = idx + ibase + (size_t)b * NSEG * S;    \
        if (sel0 && r0 < S) mp[r0] = (unsigned short)rel;           \
        if (sel1 && r1 < S) mp[r1] = (unsigned short)(rel + 1);     \
        c[b] += __popcll(m0) + __popcll(m1);                        \
      }                                                             \
    }                                                               \
  }

  for (int it = 0; it < nfull; ++it) {
    const f32x2 xx = *(const f32x2*)&sx[it * 128 + 2 * lane];  // ds_read_b64
    const f32x2 yy = *(const f32x2*)&sy[it * 128 + 2 * lane];
    PROCESS_8(it * 128, xx, yy, true, true);
  }
  const int relb = nfull * 128;
  if (relb < npts) {
    const f32x2 xx = *(const f32x2*)&sx[relb + 2 * lane];  // in-bounds (pad)
    const f32x2 yy = *(const f32x2*)&sy[relb + 2 * lane];
    const int rel = relb + 2 * lane;
    const bool g0 = (rel < npts);
    const bool g1 = (rel + 1 < npts);
    PROCESS_8(relb, xx, yy, g0, g1);
  }
#undef PROCESS_8

  if (lane == 0) {
#pragma unroll
    for (int b = 0; b < BOXG; ++b) cnt[(box0 + b) * NSEG + seg] = min(c[b], S);
  }
}

// ------- Phase 2: per box, prefix over segment counts + gather features ------
__global__ void __launch_bounds__(256) gather_kernel(
    const float* __restrict__ pts, const int* __restrict__ cnt,
    const unsigned short* __restrict__ idx, float* __restrict__ out, int N,
    int S, int NSEG, int L) {
  const int b = blockIdx.x;
  const int tid = threadIdx.x;
  const int lane = tid & 63;
  const int wid = tid >> 6;

  __shared__ int pfx[MAX_NSEG + 1];
  __shared__ int wtot[4];
  __shared__ int woff[4];

  int v = (tid < NSEG) ? cnt[b * NSEG + tid] : 0;
  int sv = v;
#pragma unroll
  for (int d = 1; d < 64; d <<= 1) {
    const int t = __shfl_up(sv, d, 64);
    if (lane >= d) sv += t;
  }
  if (lane == 63) wtot[wid] = sv;
  __syncthreads();
  if (tid == 0) {
    int a = 0;
#pragma unroll
    for (int w = 0; w < 4; ++w) {
      woff[w] = a;
      a += wtot[w];
    }
  }
  __syncthreads();
  const int incl = sv + woff[wid];
  if (tid < NSEG) pfx[tid + 1] = incl;
  if (tid == 0) pfx[0] = 0;
  __syncthreads();

  const int total = pfx[NSEG];
  if (tid < S) {
    float* o = out + ((size_t)b * S + tid) * F_DIM;
    if (tid < total) {
      int lo = 0, hi = NSEG - 1;
      while (lo < hi) {
        const int mid = (lo + hi + 1) >> 1;
        if (pfx[mid] <= tid) lo = mid;
        else hi = mid - 1;
      }
      const int s = lo;
      const int gi =
          s * L + (int)idx[((size_t)b * NSEG + s) * S + (tid - pfx[s])];
      const float* p = pts + (size_t)gi * F_DIM;
      o[0] = p[0];
      o[1] = p[1];
      o[2] = p[2];
      o[3] = p[3];
      o[4] = p[4];
    } else {
      o[0] = 0.0f;
      o[1] = 0.0f;
      o[2] = 0.0f;
      o[3] = 0.0f;
      o[4] = 0.0f;
    }
  }
}

// ---------------- Fallback: proven R1 single-kernel version ----------------
template <int BLOCK>
__global__ void __launch_bounds__(BLOCK) voxel_sampler_fallback(
    const float* __restrict__ pts, const float* __restrict__ boxes,
    float* __restrict__ out, int N, int S) {
  constexpr int NW = BLOCK / 64;
  const int b = blockIdx.x;
  const int tid = threadIdx.x;
  const int lane = tid & 63;
  const int wid = tid >> 6;

  const float cx = boxes[b * 7 + 0];
  const float cy = boxes[b * 7 + 1];
  const float hdx = __fmul_rn(boxes[b * 7 + 3], 0.5f);
  const float hdy = __fmul_rn(boxes[b * 7 + 4], 0.5f);
  const float r = __fmul_rn(
      __fsqrt_rn(__fadd_rn(__fmul_rn(hdx, hdx), __fmul_rn(hdy, hdy))),
      GAMMA_F);

  __shared__ int s_wsum[NW];
  __shared__ int s_count;
  if (tid == 0) s_count = 0;
  __syncthreads();

  float* outb = out + (size_t)b * S * F_DIM;

  for (int base = 0; base < N; base += BLOCK) {
    const int i = base + tid;
    bool sel = false;
    float x = 0.0f, y = 0.0f;
    if (i < N) {
      x = pts[i * F_DIM + 0];
      y = pts[i * F_DIM + 1];
      const float ddx = __fsub_rn(x, cx);
      const float ddy = __fsub_rn(y, cy);
      const float dis =
          __fsqrt_rn(__fadd_rn(__fmul_rn(ddx, ddx), __fmul_rn(ddy, ddy)));
      sel = (dis <= r);
    }
    const unsigned long long m = __ballot(sel);
    if (lane == 0) s_wsum[wid] = __popcll(m);
    __syncthreads();
    const int cbase = s_count;
    int wbase = 0;
    int tot = 0;
#pragma unroll
    for (int w = 0; w < NW; ++w) {
      const int v = s_wsum[w];
      if (w < wid) wbase += v;
      tot += v;
    }
    const int pos = cbase + wbase + __popcll(m & ((1ULL << lane) - 1ULL));
    if (sel && pos < S) {
      float* o = outb + pos * F_DIM;
      o[0] = x;
      o[1] = y;
      o[2] = pts[i * F_DIM + 2];
      o[3] = pts[i * F_DIM + 3];
      o[4] = pts[i * F_DIM + 4];
    }
    __syncthreads();
    if (tid == 0) s_count = cbase + tot;
    __syncthreads();
    if (cbase + tot >= S) break;
  }

  __syncthreads();
  int cnt = s_count;
  if (cnt > S) cnt = S;
  for (int j = cnt * F_DIM + tid; j < S * F_DIM; j += BLOCK) outb[j] = 0.0f;
}

extern "C" void kernel_launch(void* const* d_in, const int* in_sizes, int n_in,
                              void* d_out, int out_size, void* d_ws,
                              size_t ws_size, hipStream_t stream) {
  const float* pts = (const float*)d_in[0];
  const float* boxes = (const float*)d_in[1];
  float* out = (float*)d_out;

  const int N = in_sizes[0] / F_DIM;     // 200000
  const int B = in_sizes[1] / 7;         // 256
  const int S = out_size / (B * F_DIM);  // 128

  const int NSEG = 256;
  int L = ((N + NSEG - 1) / NSEG + 1) & ~1;  // even
  const int NGRP = B / BOXG;                 // 32
  constexpr int NWAVE = 16;                  // 1024-thread blocks

  const size_t sz_cnt = (size_t)B * NSEG * sizeof(int);
  const size_t off_idx = (sz_cnt + 255) & ~(size_t)255;
  const size_t sz_idx = (size_t)B * NSEG * S * sizeof(unsigned short);
  const size_t need = off_idx + sz_idx;

  const bool fast = (ws_size >= need) && (L >= 2) && (L <= MAXL) &&
                    (L - 1 <= 65535) && (B % BOXG == 0) && (S <= 256) &&
                    (NSEG <= MAX_NSEG) && (NGRP % NWAVE == 0) &&
                    ((size_t)L * NSEG >= (size_t)N);

  if (fast) {
    char* ws = (char*)d_ws;
    int* cnt = (int*)ws;
    unsigned short* idx = (unsigned short*)(ws + off_idx);

    const int bpg = NGRP / NWAVE;  // 2
    seg_lds_kernel<NWAVE><<<NSEG * bpg, NWAVE * 64, 0, stream>>>(
        pts, boxes, cnt, idx, N, S, NSEG, L, NGRP);
    gather_kernel<<<B, 256, 0, stream>>>(pts, cnt, idx, out, N, S, NSEG, L);
  } else {
    voxel_sampler_fallback<1024><<<B, 1024, 0, stream>>>(pts, boxes, out, N,
                                                         S);
  }
}